// Round 6
// baseline (528.409 us; speedup 1.0000x reference)
//
#include <hip/hip_runtime.h>

// DeepKoopmanNoDec — fp32 in/out. R9: (1) encoder_tgt: keep R8's acc[4][8]
// big tile but pin amdgpu_waves_per_eu(2,2) — R8's spill (VGPR=128, ~150MB
// scratch) came from the allocator targeting 4 waves/EU on its own; a max
// of 2 waves/EU frees the 256-VGPR budget the tile needs. (2) scan: ONE
// barrier/step — epilogue converts z_next to hi/lo bf16 and writes ping-
// pong zh/zl directly; bu (u@B) lives in registers, computed one step
// ahead in the MFMA shadow; zbuf/bu LDS buffers deleted. zk/prep unchanged.
// Shapes: B=2048, M=64, STATE=32, EMBED=96, LATENT=128, HIDDEN=512.

typedef unsigned short u16;
typedef __attribute__((ext_vector_type(8))) short bf16x8;   // MFMA A/B frag (4 VGPRs)
typedef __attribute__((ext_vector_type(4))) short bf16x4;   // 8B packed store
typedef __attribute__((ext_vector_type(4))) float f32x4;    // MFMA C/D frag

// ws layout (u16 elements unless noted): bf16 frag weights | fp32 z_k | Ah | Al
#define OFF_W1 0              // 32 frags   (K=32 , N=512)
#define OFF_W2 16384          // 512 frags  (K=512, N=512)
#define OFF_W3 278528         // 512 frags
#define OFF_WO 540672         // 96 frags   (K=512, N=96)
#define OFF_ZK_BYTES 1179648  // fp32 z_k: 2048*128 floats (1 MB)
#define OFF_AH 1114112        // u16: 32 frags of A-hi
#define OFF_AL 1130496        // u16: 32 frags of A-lo

// d_out regions (float elements): z_pred | x_pred | z_target
#define XPRED_OFF 16777216
#define ZTGT_OFF  20971520

__device__ __forceinline__ float bf2f(u16 u) {
  unsigned int i = ((unsigned int)u) << 16;
  return __builtin_bit_cast(float, i);
}
__device__ __forceinline__ u16 f2bf(float f) {   // round-to-nearest-even
  unsigned int i = __builtin_bit_cast(unsigned int, f);
  i = (i + 0x7FFFu + ((i >> 16) & 1u)) >> 16;
  return (u16)i;
}

// ---------------------------------------------------------------------------
// Prep: swizzle fp32 matrices (row-major K x N) into bf16 B-fragment-linear
// layout. frag f = ct*(K/32)+ks; lane l holds W[ks*32+(l>>4)*8+j][ct*16+(l&15)]
// at u16 offset f*512 + l*8. Frags 1152..1183 = A-hi, 1184..1215 = A-lo.
// ---------------------------------------------------------------------------
__global__ void prep_swizzle(const float* __restrict__ W1, const float* __restrict__ W2,
                             const float* __restrict__ W3, const float* __restrict__ Wo,
                             const float* __restrict__ Am, u16* __restrict__ dst) {
  int f = blockIdx.x;
  int l = threadIdx.x;
  const float* src; int K, N; u16* d; int lo = 0;
  if (f < 32)        { src = W1; K = 32;  N = 512; d = dst + OFF_W1; }
  else if (f < 544)  { src = W2; K = 512; N = 512; d = dst + OFF_W2; f -= 32; }
  else if (f < 1056) { src = W3; K = 512; N = 512; d = dst + OFF_W3; f -= 544; }
  else if (f < 1152) { src = Wo; K = 512; N = 96;  d = dst + OFF_WO; f -= 1056; }
  else if (f < 1184) { src = Am; K = 128; N = 128; d = dst + OFF_AH; f -= 1152; }
  else               { src = Am; K = 128; N = 128; d = dst + OFF_AL; f -= 1184; lo = 1; }
  const int KF = K >> 5;
  const int ct = f / KF, ks = f - ct * KF;
  const int q = l >> 4, n = l & 15;
  const int kbase = ks * 32 + q * 8;
  const int col = ct * 16 + n;
  bf16x8 vh;
  #pragma unroll
  for (int j = 0; j < 8; ++j) {
    float v = src[(size_t)(kbase + j) * N + col];
    u16 h = f2bf(v);
    if (lo) h = f2bf(v - bf2f(h));
    vh[j] = (short)h;
  }
  *(bf16x8*)(d + ((size_t)f * 64 + l) * 8) = vh;
}

// ---------------------------------------------------------------------------
// encoder_tgt. hbuf: row-major [128][512] bf16, XOR swizzle on u16 index:
// idx = (row*512 + k) ^ ((row&7)<<3). 8 waves = 2 rowhalves x 4 colgroups;
// wave tile 64 rows x 128 cols, acc[4][8]. waves_per_eu(2,2) -> 256-VGPR
// budget, no spill. Weights global->VGPR (L2-resident).
// ---------------------------------------------------------------------------
__device__ __forceinline__ void store_h(const f32x4 (&acc)[4][8],
                                        const float* __restrict__ bias,
                                        u16* hbuf, int rh, int cg, int q, int n) {
  __syncthreads();                       // all readers of previous h done
  #pragma unroll
  for (int i = 0; i < 8; ++i) {
    const int col = cg * 128 + i * 16 + n;
    const float bia = bias[col];
    #pragma unroll
    for (int rg = 0; rg < 4; ++rg) {
      const int rb = rh * 64 + rg * 16 + q * 4;   // C layout: col=lane&15, row=(lane>>4)*4+r
      float f0 = fmaxf(acc[rg][i][0] + bia, 0.f);
      float f1 = fmaxf(acc[rg][i][1] + bia, 0.f);
      float f2 = fmaxf(acc[rg][i][2] + bia, 0.f);
      float f3 = fmaxf(acc[rg][i][3] + bia, 0.f);
      unsigned p01, p23;
      asm("v_cvt_pk_bf16_f32 %0, %1, %2" : "=v"(p01) : "v"(f0), "v"(f1));
      asm("v_cvt_pk_bf16_f32 %0, %1, %2" : "=v"(p23) : "v"(f2), "v"(f3));
      hbuf[((rb + 0) * 512 + col) ^ (((rb + 0) & 7) << 3)] = (u16)(p01 & 0xFFFFu);
      hbuf[((rb + 1) * 512 + col) ^ (((rb + 1) & 7) << 3)] = (u16)(p01 >> 16);
      hbuf[((rb + 2) * 512 + col) ^ (((rb + 2) & 7) << 3)] = (u16)(p23 & 0xFFFFu);
      hbuf[((rb + 3) * 512 + col) ^ (((rb + 3) & 7) << 3)] = (u16)(p23 >> 16);
    }
  }
  __syncthreads();                       // new h visible to all waves
}

__device__ __forceinline__ void big_layer(const u16* __restrict__ wb,
                                          const float* __restrict__ bias,
                                          u16* hbuf, int rh, int cg, int l, int q, int n) {
  f32x4 acc[4][8];
  #pragma unroll
  for (int rg = 0; rg < 4; ++rg)
    #pragma unroll
    for (int i = 0; i < 8; ++i) acc[rg][i] = (f32x4){0.f, 0.f, 0.f, 0.f};
  #pragma unroll 2
  for (int ks = 0; ks < 16; ++ks) {
    bf16x8 b[8], a[4];
    #pragma unroll
    for (int i = 0; i < 8; ++i)
      b[i] = *(const bf16x8*)(wb + (size_t)((8 * cg + i) * 16 + ks) * 512 + (size_t)l * 8);
    #pragma unroll
    for (int rg = 0; rg < 4; ++rg) {
      const int row = rh * 64 + rg * 16 + n;   // A layout: row=lane&15, k=(lane>>4)*8+j
      a[rg] = *(const bf16x8*)&hbuf[(row * 512 + ks * 32 + q * 8) ^ ((row & 7) << 3)];
    }
    #pragma unroll
    for (int rg = 0; rg < 4; ++rg)
      #pragma unroll
      for (int i = 0; i < 8; ++i)
        acc[rg][i] = __builtin_amdgcn_mfma_f32_16x16x32_bf16(a[rg], b[i], acc[rg][i], 0, 0, 0);
  }
  store_h(acc, bias, hbuf, rh, cg, q, n);
}

__global__ __launch_bounds__(512)
__attribute__((amdgpu_waves_per_eu(2, 2)))
void encoder_tgt(
    const float* __restrict__ xnext, const u16* __restrict__ wf,
    const float* __restrict__ b1, const float* __restrict__ b2,
    const float* __restrict__ b3, const float* __restrict__ bo_,
    float* __restrict__ ztgt) {
  __shared__ __align__(16) u16 hbuf[128 * 512];   // 128KB, swizzled
  const int tid = threadIdx.x;
  const int wv = tid >> 6, l = tid & 63;
  const int q = l >> 4, n = l & 15;
  const int rh = wv >> 2, cg = wv & 3;
  const size_t row0 = (size_t)blockIdx.x * 128;

  // stage x -> hbuf (bf16) + exact fp32 pass-through to ztgt cols 0..31
  {
    const int r = tid >> 2, k0 = (tid & 3) * 8;
    f32x4 x0 = *(const f32x4*)(xnext + (row0 + r) * 32 + k0);
    f32x4 x1 = *(const f32x4*)(xnext + (row0 + r) * 32 + k0 + 4);
    *(f32x4*)(ztgt + (row0 + r) * 128 + k0)     = x0;
    *(f32x4*)(ztgt + (row0 + r) * 128 + k0 + 4) = x1;
    bf16x8 v;
    #pragma unroll
    for (int j = 0; j < 4; ++j) { v[j] = (short)f2bf(x0[j]); v[4 + j] = (short)f2bf(x1[j]); }
    *(bf16x8*)&hbuf[(r * 512 + k0) ^ ((r & 7) << 3)] = v;
  }
  __syncthreads();

  // ---- layer 1 (K=32, single ks-chunk) ----
  {
    f32x4 acc[4][8];
    #pragma unroll
    for (int rg = 0; rg < 4; ++rg)
      #pragma unroll
      for (int i = 0; i < 8; ++i) acc[rg][i] = (f32x4){0.f, 0.f, 0.f, 0.f};
    bf16x8 a[4];
    #pragma unroll
    for (int rg = 0; rg < 4; ++rg) {
      const int row = rh * 64 + rg * 16 + n;
      a[rg] = *(const bf16x8*)&hbuf[(row * 512 + q * 8) ^ ((row & 7) << 3)];
    }
    #pragma unroll
    for (int i = 0; i < 8; ++i) {
      bf16x8 b = *(const bf16x8*)(wf + OFF_W1 + (size_t)(8 * cg + i) * 512 + (size_t)l * 8);
      #pragma unroll
      for (int rg = 0; rg < 4; ++rg)
        acc[rg][i] = __builtin_amdgcn_mfma_f32_16x16x32_bf16(a[rg], b, acc[rg][i], 0, 0, 0);
    }
    store_h(acc, b1, hbuf, rh, cg, q, n);
  }

  // ---- layers 2, 3 ----
  big_layer(wf + OFF_W2, b2, hbuf, rh, cg, l, q, n);
  big_layer(wf + OFF_W3, b3, hbuf, rh, cg, l, q, n);

  // ---- output layer: 6 col-tiles, waves 0..5 one tile each, all 128 rows ----
  if (wv < 6) {
    f32x4 o[8];
    #pragma unroll
    for (int rg = 0; rg < 8; ++rg) o[rg] = (f32x4){0.f, 0.f, 0.f, 0.f};
    #pragma unroll 2
    for (int ks = 0; ks < 16; ++ks) {
      bf16x8 b = *(const bf16x8*)(wf + OFF_WO + (size_t)(wv * 16 + ks) * 512 + (size_t)l * 8);
      #pragma unroll
      for (int rg = 0; rg < 8; ++rg) {
        const int row = rg * 16 + n;
        bf16x8 a = *(const bf16x8*)&hbuf[(row * 512 + ks * 32 + q * 8) ^ ((row & 7) << 3)];
        o[rg] = __builtin_amdgcn_mfma_f32_16x16x32_bf16(a, b, o[rg], 0, 0, 0);
      }
    }
    const float bia = bo_[wv * 16 + n];
    #pragma unroll
    for (int rg = 0; rg < 8; ++rg)
      #pragma unroll
      for (int r = 0; r < 4; ++r)
        ztgt[(row0 + rg * 16 + q * 4 + r) * 128 + 32 + wv * 16 + n] = o[rg][r] + bia;
  }
}

// ---------------------------------------------------------------------------
// z_k encoder — exact fp32 VALU. 512 threads (1 col/thread, 8 rows).
// ---------------------------------------------------------------------------
__global__ __launch_bounds__(512) void encoder_zk_f32(
    const float* __restrict__ xk,
    const float* __restrict__ W1, const float* __restrict__ b1,
    const float* __restrict__ W2, const float* __restrict__ b2,
    const float* __restrict__ W3, const float* __restrict__ b3,
    const float* __restrict__ Wo, const float* __restrict__ bo_,
    float* __restrict__ zk_out) {
  __shared__ __align__(16) float hb[2][8][512];
  __shared__ __align__(16) float xb[8][32];
  const int t = threadIdx.x;
  const int row0 = blockIdx.x * 8;
  if (t < 256) {
    int r = t >> 5, j = t & 31;
    float v = xk[(size_t)(row0 + r) * 32 + j];
    xb[r][j] = v;
    zk_out[(size_t)(row0 + r) * 128 + j] = v;      // x pass-through
  }
  __syncthreads();
  const int c = t;
  // layer 1: K=32
  {
    float a[8];
    const float i0 = b1[c];
    #pragma unroll
    for (int r = 0; r < 8; ++r) a[r] = i0;
    for (int k = 0; k < 32; k += 4) {
      float w0 = W1[(size_t)(k+0)*512 + c];
      float w1 = W1[(size_t)(k+1)*512 + c];
      float w2 = W1[(size_t)(k+2)*512 + c];
      float w3 = W1[(size_t)(k+3)*512 + c];
      #pragma unroll
      for (int r = 0; r < 8; ++r) {
        f32x4 z = *(const f32x4*)&xb[r][k];
        a[r] += z[0]*w0 + z[1]*w1 + z[2]*w2 + z[3]*w3;
      }
    }
    #pragma unroll
    for (int r = 0; r < 8; ++r) hb[0][r][c] = fmaxf(a[r], 0.f);
  }
  __syncthreads();
  // layers 2,3: K=512
  #pragma unroll
  for (int lyr = 0; lyr < 2; ++lyr) {
    const float* W = lyr ? W3 : W2;
    const float* bb = lyr ? b3 : b2;
    const float (*hin)[512] = hb[lyr & 1];
    float (*hout)[512] = hb[(lyr & 1) ^ 1];
    float a[8];
    const float i0 = bb[c];
    #pragma unroll
    for (int r = 0; r < 8; ++r) a[r] = i0;
    for (int k = 0; k < 512; k += 4) {
      float w0 = W[(size_t)(k+0)*512 + c];
      float w1 = W[(size_t)(k+1)*512 + c];
      float w2 = W[(size_t)(k+2)*512 + c];
      float w3 = W[(size_t)(k+3)*512 + c];
      #pragma unroll
      for (int r = 0; r < 8; ++r) {
        f32x4 z = *(const f32x4*)&hin[r][k];
        a[r] += z[0]*w0 + z[1]*w1 + z[2]*w2 + z[3]*w3;
      }
    }
    #pragma unroll
    for (int r = 0; r < 8; ++r) hout[r][c] = fmaxf(a[r], 0.f);
    __syncthreads();
  }
  // output layer: N=96
  if (t < 96) {
    float a[8];
    const float i0 = bo_[t];
    #pragma unroll
    for (int r = 0; r < 8; ++r) a[r] = i0;
    for (int k = 0; k < 512; k += 4) {
      float w0 = Wo[(size_t)(k+0)*96 + t];
      float w1 = Wo[(size_t)(k+1)*96 + t];
      float w2 = Wo[(size_t)(k+2)*96 + t];
      float w3 = Wo[(size_t)(k+3)*96 + t];
      #pragma unroll
      for (int r = 0; r < 8; ++r) {
        f32x4 z = *(const f32x4*)&hb[0][r][k];
        a[r] += z[0]*w0 + z[1]*w1 + z[2]*w2 + z[3]*w3;
      }
    }
    #pragma unroll
    for (int r = 0; r < 8; ++r)
      zk_out[(size_t)(row0 + r) * 128 + 32 + t] = a[r];
  }
}

// ---------------------------------------------------------------------------
// Scan — hi/lo bf16 MFMA (fp32 emulation), ONE barrier per step.
// z_{s+1} = z_s @ A + u_s @ Bmat. Block = 8 rows, 512 thr (8 waves, 1 col-
// tile each). zh/zl ping-pong: epilogue owner lanes (q<2; row=q*4+r, col=
// wv*16+n) write z_next hi/lo directly into zh/zl[cur^1]; bu (u@B) kept in
// registers, computed one step ahead. No zbuf, no bu LDS, no conv phase.
// ---------------------------------------------------------------------------
__global__ __launch_bounds__(512) void scan_mfma(
    const float* __restrict__ zk, const u16* __restrict__ wf,
    const float* __restrict__ Bm, const float* __restrict__ useq,
    float* __restrict__ zpred, float* __restrict__ xpred) {
  __shared__ __align__(16) u16 ahf[32 * 512];     // 32KB A-hi frags
  __shared__ __align__(16) u16 alf[32 * 512];     // 32KB A-lo frags
  __shared__ __align__(16) float ubuf[8 * 512];   // 16KB u (rows x steps x 8)
  __shared__ __align__(16) u16 zh[2][16][136];    // z hi bf16, ping-pong
  __shared__ __align__(16) u16 zl[2][16][136];    // z lo bf16, ping-pong
  const int t = threadIdx.x;
  const int wv = t >> 6, l = t & 63;
  const int q = l >> 4, n = l & 15;
  const size_t b0 = (size_t)blockIdx.x * 8;

  // async stage Ah/Al (wave wv: frags wv*4 .. wv*4+4 of each)
  #pragma unroll
  for (int i = 0; i < 4; ++i) {
    const int f = wv * 4 + i;
    __builtin_amdgcn_global_load_lds(
        (const __attribute__((address_space(1))) unsigned int*)(wf + OFF_AH + (size_t)f * 512 + l * 8),
        (__attribute__((address_space(3))) unsigned int*)(ahf + (size_t)f * 512), 16, 0, 0);
    __builtin_amdgcn_global_load_lds(
        (const __attribute__((address_space(1))) unsigned int*)(wf + OFF_AL + (size_t)f * 512 + l * 8),
        (__attribute__((address_space(3))) unsigned int*)(alf + (size_t)f * 512), 16, 0, 0);
  }
  // stage u (16KB contiguous)
  {
    const float* us = useq + b0 * 512;
    *(f32x4*)&ubuf[t * 8]     = *(const f32x4*)(us + t * 8);
    *(f32x4*)&ubuf[t * 8 + 4] = *(const f32x4*)(us + t * 8 + 4);
  }
  // zero garbage rows 8..15 of both zh/zl buffers (MFMA A-operand reads them)
  for (int i = t; i < 8 * 136; i += 512) {
    (&zh[0][8][0])[i] = 0; (&zh[1][8][0])[i] = 0;
    (&zl[0][8][0])[i] = 0; (&zl[1][8][0])[i] = 0;
  }
  // initial z0 -> zh/zl[0]
  if (t < 256) {
    const int r = t >> 5, c4 = (t & 31) * 4;
    f32x4 z = *(const f32x4*)(zk + (b0 + r) * 128 + c4);
    #pragma unroll
    for (int i = 0; i < 4; ++i) {
      u16 h = f2bf(z[i]);
      zh[0][r][c4 + i] = h;
      zl[0][r][c4 + i] = f2bf(z[i] - bf2f(h));
    }
  }
  // B column for this lane's owned output col (only q<2 lanes use it)
  const int myc = wv * 16 + n;
  float bmv[8];
  #pragma unroll
  for (int j = 0; j < 8; ++j) bmv[j] = Bm[(size_t)j * 128 + myc];
  __syncthreads();

  // bu for s=0 (owner rows q*4+r; (q&1) keeps non-owner lanes in-bounds)
  float bunow[4];
  #pragma unroll
  for (int r = 0; r < 4; ++r) {
    const int row = (q & 1) * 4 + r;
    f32x4 ua = *(const f32x4*)&ubuf[row * 512];
    f32x4 ub = *(const f32x4*)&ubuf[row * 512 + 4];
    bunow[r] = ua[0]*bmv[0] + ua[1]*bmv[1] + ua[2]*bmv[2] + ua[3]*bmv[3]
             + ub[0]*bmv[4] + ub[1]*bmv[5] + ub[2]*bmv[6] + ub[3]*bmv[7];
  }

  int cur = 0;
  for (int s = 0; s < 64; ++s) {
    // ---- MFMA: wave wv -> out-cols [wv*16, wv*16+16), 3 independent chains
    f32x4 aH = {0.f, 0.f, 0.f, 0.f};
    f32x4 aL = {0.f, 0.f, 0.f, 0.f};
    f32x4 aM = {0.f, 0.f, 0.f, 0.f};
    #pragma unroll
    for (int ks = 0; ks < 4; ++ks) {
      const int ko = ks * 32 + q * 8;
      bf16x8 azh = *(const bf16x8*)&zh[cur][n][ko];   // A: row=lane&15, k=(lane>>4)*8+j
      bf16x8 azl = *(const bf16x8*)&zl[cur][n][ko];
      bf16x8 bh = *(const bf16x8*)&ahf[(size_t)(wv * 4 + ks) * 512 + l * 8];
      bf16x8 bl = *(const bf16x8*)&alf[(size_t)(wv * 4 + ks) * 512 + l * 8];
      aH = __builtin_amdgcn_mfma_f32_16x16x32_bf16(azh, bh, aH, 0, 0, 0);
      aL = __builtin_amdgcn_mfma_f32_16x16x32_bf16(azl, bh, aL, 0, 0, 0);
      aM = __builtin_amdgcn_mfma_f32_16x16x32_bf16(azh, bl, aM, 0, 0, 0);
    }
    f32x4 acc = aH + aL;
    acc = acc + aM;
    // ---- epilogue: owner lanes write z_next (hi/lo) + global outputs ----
    if (q < 2) {
      #pragma unroll
      for (int r = 0; r < 4; ++r) {
        const int row = q * 4 + r;
        const float v = acc[r] + bunow[r];
        u16 h = f2bf(v);
        zh[cur ^ 1][row][myc] = h;
        zl[cur ^ 1][row][myc] = f2bf(v - bf2f(h));
        const size_t go = (b0 + row) * 64 + s;
        zpred[go * 128 + myc] = v;
        if (wv < 2) xpred[go * 32 + myc] = v;   // cols 0..31 = x_pred
      }
    }
    // ---- bu for step s+1 (in MFMA/epilogue shadow, registers only) ----
    if (s < 63) {
      #pragma unroll
      for (int r = 0; r < 4; ++r) {
        const int row = (q & 1) * 4 + r;
        f32x4 ua = *(const f32x4*)&ubuf[row * 512 + (s + 1) * 8];
        f32x4 ub = *(const f32x4*)&ubuf[row * 512 + (s + 1) * 8 + 4];
        bunow[r] = ua[0]*bmv[0] + ua[1]*bmv[1] + ua[2]*bmv[2] + ua[3]*bmv[3]
                 + ub[0]*bmv[4] + ub[1]*bmv[5] + ub[2]*bmv[6] + ub[3]*bmv[7];
      }
    }
    __syncthreads();
    cur ^= 1;
  }
}

// ---------------------------------------------------------------------------
extern "C" void kernel_launch(void* const* d_in, const int* in_sizes, int n_in,
                              void* d_out, int out_size, void* d_ws, size_t ws_size,
                              hipStream_t stream) {
  (void)in_sizes; (void)n_in; (void)out_size; (void)ws_size;
  const float* xk    = (const float*)d_in[0];
  const float* useq  = (const float*)d_in[1];
  const float* xnext = (const float*)d_in[2];
  const float* W1 = (const float*)d_in[3];
  const float* b1 = (const float*)d_in[4];
  const float* W2 = (const float*)d_in[5];
  const float* b2 = (const float*)d_in[6];
  const float* W3 = (const float*)d_in[7];
  const float* b3 = (const float*)d_in[8];
  const float* Wo = (const float*)d_in[9];
  const float* bo = (const float*)d_in[10];
  const float* A  = (const float*)d_in[11];
  const float* Bm = (const float*)d_in[12];

  float* out   = (float*)d_out;
  float* zpred = out;
  float* xpred = out + XPRED_OFF;
  float* ztgt  = out + ZTGT_OFF;
  u16*   wf    = (u16*)d_ws;
  float* zkw   = (float*)((char*)d_ws + OFF_ZK_BYTES);

  prep_swizzle<<<1216, 64, 0, stream>>>(W1, W2, W3, Wo, A, wf);
  encoder_zk_f32<<<256, 512, 0, stream>>>(xk, W1, b1, W2, b2, W3, b3, Wo, bo, zkw);
  scan_mfma<<<256, 512, 0, stream>>>(zkw, wf, Bm, useq, zpred, xpred);
  encoder_tgt<<<1024, 512, 0, stream>>>(xnext, wf, b1, b2, b3, bo, ztgt);
}

// Round 7
// 493.838 us; speedup vs baseline: 1.0700x; 1.0700x over previous
//
#include <hip/hip_runtime.h>

// DeepKoopmanNoDec — fp32 in/out. R10: acc[4][8] register path is dead (3x
// confirmed spill at any block size/attribute). Instead get the reuse from
// the MFMA SHAPE: encoder_tgt rebuilt on 32x32x16 (2x FLOP per operand byte
// vs 16x16x32, measured 2382 vs 2075 TF): R5 geometry (2048 x 64-row
// blocks, 512 thr, wave = 64x64) as acc[2][2] f32x16 = 64 acc VGPR — clean
// compile territory — with half the MFMA instrs and half the frag loads of
// R5. store_h uses cvt_pk packed bf16 converts. prep: W-frags now 32x32
// B-layout; scan Ah/Al keep 16x16 layout. scan/zk unchanged from R9.
// Shapes: B=2048, M=64, STATE=32, EMBED=96, LATENT=128, HIDDEN=512.

typedef unsigned short u16;
typedef __attribute__((ext_vector_type(8))) short bf16x8;   // MFMA A/B frag (4 VGPRs)
typedef __attribute__((ext_vector_type(4))) short bf16x4;   // 8B packed store
typedef __attribute__((ext_vector_type(4))) float f32x4;    // 16x16 C/D frag
typedef __attribute__((ext_vector_type(16))) float f32x16;  // 32x32 C/D frag

// ws layout (u16 elements unless noted): bf16 frag weights | fp32 z_k | Ah | Al
#define OFF_W1 0              // 32 frags   (K=32 , N=512)  [32x32 B-layout]
#define OFF_W2 16384          // 512 frags  (K=512, N=512)
#define OFF_W3 278528         // 512 frags
#define OFF_WO 540672         // 96 frags   (K=512, N=96)
#define OFF_ZK_BYTES 1179648  // fp32 z_k: 2048*128 floats (1 MB)
#define OFF_AH 1114112        // u16: 32 frags of A-hi [16x16 layout, scan]
#define OFF_AL 1130496        // u16: 32 frags of A-lo

// d_out regions (float elements): z_pred | x_pred | z_target
#define XPRED_OFF 16777216
#define ZTGT_OFF  20971520

__device__ __forceinline__ float bf2f(u16 u) {
  unsigned int i = ((unsigned int)u) << 16;
  return __builtin_bit_cast(float, i);
}
__device__ __forceinline__ u16 f2bf(float f) {   // round-to-nearest-even
  unsigned int i = __builtin_bit_cast(unsigned int, f);
  i = (i + 0x7FFFu + ((i >> 16) & 1u)) >> 16;
  return (u16)i;
}

// ---------------------------------------------------------------------------
// Prep. W-frags (f<1152): 32x32x16 B-layout — frag f = ct*(K/16)+ks; lane l
// holds W[ks*16+(l>>5)*8+j][ct*32+(l&31)] at u16 offset f*512+l*8.
// A-frags (f>=1152, scan Ah/Al): 16x16x32 layout as before.
// ---------------------------------------------------------------------------
__global__ void prep_swizzle(const float* __restrict__ W1, const float* __restrict__ W2,
                             const float* __restrict__ W3, const float* __restrict__ Wo,
                             const float* __restrict__ Am, u16* __restrict__ dst) {
  int f = blockIdx.x;
  int l = threadIdx.x;
  if (f < 1152) {                 // encoder weights: 32x32 B-frag layout
    const float* src; int K, N; u16* d;
    if (f < 32)        { src = W1; K = 32;  N = 512; d = dst + OFF_W1; }
    else if (f < 544)  { src = W2; K = 512; N = 512; d = dst + OFF_W2; f -= 32; }
    else if (f < 1056) { src = W3; K = 512; N = 512; d = dst + OFF_W3; f -= 544; }
    else               { src = Wo; K = 512; N = 96;  d = dst + OFF_WO; f -= 1056; }
    const int KF = K >> 4;
    const int ct = f / KF, ks = f - ct * KF;
    const int kbase = ks * 16 + (l >> 5) * 8;
    const int col = ct * 32 + (l & 31);
    bf16x8 vh;
    #pragma unroll
    for (int j = 0; j < 8; ++j)
      vh[j] = (short)f2bf(src[(size_t)(kbase + j) * N + col]);
    *(bf16x8*)(d + ((size_t)f * 64 + l) * 8) = vh;
  } else {                        // scan A hi/lo: 16x16x32 layout
    int lo = 0; u16* d;
    if (f < 1184) { d = dst + OFF_AH; f -= 1152; }
    else          { d = dst + OFF_AL; f -= 1184; lo = 1; }
    const int ct = f >> 2, ks = f & 3;
    const int q = l >> 4, n = l & 15;
    const int kbase = ks * 32 + q * 8;
    const int col = ct * 16 + n;
    bf16x8 vh;
    #pragma unroll
    for (int j = 0; j < 8; ++j) {
      float v = Am[(size_t)(kbase + j) * 128 + col];
      u16 h = f2bf(v);
      if (lo) h = f2bf(v - bf2f(h));
      vh[j] = (short)h;
    }
    *(bf16x8*)(d + ((size_t)f * 64 + l) * 8) = vh;
  }
}

// ---------------------------------------------------------------------------
// encoder_tgt. hbuf: row-major [64][512] bf16, XOR swizzle on u16 index:
// idx = (row*512 + k) ^ ((row&7)<<3). 8 waves, wave wv owns cols wv*64..+64
// (2 ct of 32) x all 64 rows (2 rg of 32). 32x32x16 MFMA:
//   A: row=lane&31, k=(lane>>5)*8+j ; B: col=lane&31, same k
//   C: col=lane&31, row=(reg&3)+8*(reg>>2)+4*(lane>>5)
// ---------------------------------------------------------------------------
__device__ __forceinline__ void store_h32(const f32x16 (&acc)[2][2],
                                          const float* __restrict__ bias,
                                          u16* hbuf, int cg, int lo, int hi) {
  __syncthreads();                       // all readers of previous h done
  #pragma unroll
  for (int i = 0; i < 2; ++i) {
    const int col = cg * 64 + i * 32 + lo;
    const float bia = bias[col];
    #pragma unroll
    for (int rg = 0; rg < 2; ++rg) {
      #pragma unroll
      for (int g = 0; g < 4; ++g) {
        const int rb = rg * 32 + hi * 4 + g * 8;
        float v0 = fmaxf(acc[rg][i][g * 4 + 0] + bia, 0.f);
        float v1 = fmaxf(acc[rg][i][g * 4 + 1] + bia, 0.f);
        float v2 = fmaxf(acc[rg][i][g * 4 + 2] + bia, 0.f);
        float v3 = fmaxf(acc[rg][i][g * 4 + 3] + bia, 0.f);
        unsigned p01, p23;
        asm("v_cvt_pk_bf16_f32 %0, %1, %2" : "=v"(p01) : "v"(v0), "v"(v1));
        asm("v_cvt_pk_bf16_f32 %0, %1, %2" : "=v"(p23) : "v"(v2), "v"(v3));
        hbuf[((rb + 0) * 512 + col) ^ (((rb + 0) & 7) << 3)] = (u16)(p01 & 0xFFFFu);
        hbuf[((rb + 1) * 512 + col) ^ (((rb + 1) & 7) << 3)] = (u16)(p01 >> 16);
        hbuf[((rb + 2) * 512 + col) ^ (((rb + 2) & 7) << 3)] = (u16)(p23 & 0xFFFFu);
        hbuf[((rb + 3) * 512 + col) ^ (((rb + 3) & 7) << 3)] = (u16)(p23 >> 16);
      }
    }
  }
  __syncthreads();                       // new h visible to all waves
}

__device__ __forceinline__ void big_layer32(const u16* __restrict__ wb,
                                            const float* __restrict__ bias,
                                            u16* hbuf, int cg, int l, int lo, int hi) {
  f32x16 acc[2][2];
  #pragma unroll
  for (int rg = 0; rg < 2; ++rg)
    #pragma unroll
    for (int i = 0; i < 2; ++i)
      #pragma unroll
      for (int e = 0; e < 16; ++e) acc[rg][i][e] = 0.f;
  #pragma unroll 4
  for (int ks = 0; ks < 32; ++ks) {
    bf16x8 b[2], a[2];
    #pragma unroll
    for (int i = 0; i < 2; ++i)
      b[i] = *(const bf16x8*)(wb + (size_t)((2 * cg + i) * 32 + ks) * 512 + (size_t)l * 8);
    #pragma unroll
    for (int rg = 0; rg < 2; ++rg) {
      const int row = rg * 32 + lo;
      a[rg] = *(const bf16x8*)&hbuf[(row * 512 + ks * 16 + hi * 8) ^ ((row & 7) << 3)];
    }
    #pragma unroll
    for (int rg = 0; rg < 2; ++rg)
      #pragma unroll
      for (int i = 0; i < 2; ++i)
        acc[rg][i] = __builtin_amdgcn_mfma_f32_32x32x16_bf16(a[rg], b[i], acc[rg][i], 0, 0, 0);
  }
  store_h32(acc, bias, hbuf, cg, lo, hi);
}

__global__ __launch_bounds__(512, 2) void encoder_tgt(
    const float* __restrict__ xnext, const u16* __restrict__ wf,
    const float* __restrict__ b1, const float* __restrict__ b2,
    const float* __restrict__ b3, const float* __restrict__ bo_,
    float* __restrict__ ztgt) {
  __shared__ __align__(16) u16 hbuf[64 * 512];   // 64KB, swizzled
  const int tid = threadIdx.x;
  const int wv = tid >> 6, l = tid & 63;
  const int lo = l & 31, hi = l >> 5;
  const size_t row0 = (size_t)blockIdx.x * 64;

  // stage x -> hbuf (bf16) + exact fp32 pass-through to ztgt cols 0..31
  {
    const int r = tid >> 3, k0 = (tid & 7) * 4;
    f32x4 x = *(const f32x4*)(xnext + (row0 + r) * 32 + k0);
    *(f32x4*)(ztgt + (row0 + r) * 128 + k0) = x;
    bf16x4 v;
    #pragma unroll
    for (int j = 0; j < 4; ++j) v[j] = (short)f2bf(x[j]);
    *(bf16x4*)&hbuf[(r * 512 + k0) ^ ((r & 7) << 3)] = v;
  }
  __syncthreads();

  // ---- layer 1 (K=32: 2 ks16 chunks) ----
  {
    f32x16 acc[2][2];
    #pragma unroll
    for (int rg = 0; rg < 2; ++rg)
      #pragma unroll
      for (int i = 0; i < 2; ++i)
        #pragma unroll
        for (int e = 0; e < 16; ++e) acc[rg][i][e] = 0.f;
    #pragma unroll
    for (int ks = 0; ks < 2; ++ks) {
      bf16x8 b[2], a[2];
      #pragma unroll
      for (int i = 0; i < 2; ++i)
        b[i] = *(const bf16x8*)(wf + OFF_W1 + (size_t)((2 * wv + i) * 2 + ks) * 512 + (size_t)l * 8);
      #pragma unroll
      for (int rg = 0; rg < 2; ++rg) {
        const int row = rg * 32 + lo;
        a[rg] = *(const bf16x8*)&hbuf[(row * 512 + ks * 16 + hi * 8) ^ ((row & 7) << 3)];
      }
      #pragma unroll
      for (int rg = 0; rg < 2; ++rg)
        #pragma unroll
        for (int i = 0; i < 2; ++i)
          acc[rg][i] = __builtin_amdgcn_mfma_f32_32x32x16_bf16(a[rg], b[i], acc[rg][i], 0, 0, 0);
    }
    store_h32(acc, b1, hbuf, wv, lo, hi);
  }

  // ---- layers 2, 3 ----
  big_layer32(wf + OFF_W2, b2, hbuf, wv, l, lo, hi);
  big_layer32(wf + OFF_W3, b3, hbuf, wv, l, lo, hi);

  // ---- output layer: 3 col-tiles of 32, waves 0..2 ----
  if (wv < 3) {
    f32x16 o[2];
    #pragma unroll
    for (int rg = 0; rg < 2; ++rg)
      #pragma unroll
      for (int e = 0; e < 16; ++e) o[rg][e] = 0.f;
    #pragma unroll 4
    for (int ks = 0; ks < 32; ++ks) {
      bf16x8 b = *(const bf16x8*)(wf + OFF_WO + (size_t)(wv * 32 + ks) * 512 + (size_t)l * 8);
      #pragma unroll
      for (int rg = 0; rg < 2; ++rg) {
        const int row = rg * 32 + lo;
        bf16x8 a = *(const bf16x8*)&hbuf[(row * 512 + ks * 16 + hi * 8) ^ ((row & 7) << 3)];
        o[rg] = __builtin_amdgcn_mfma_f32_32x32x16_bf16(a, b, o[rg], 0, 0, 0);
      }
    }
    const float bia = bo_[wv * 32 + lo];
    #pragma unroll
    for (int rg = 0; rg < 2; ++rg)
      #pragma unroll
      for (int g = 0; g < 4; ++g)
        #pragma unroll
        for (int m = 0; m < 4; ++m) {
          const int row = rg * 32 + hi * 4 + g * 8 + m;
          ztgt[(row0 + row) * 128 + 32 + wv * 32 + lo] = o[rg][g * 4 + m] + bia;
        }
  }
}

// ---------------------------------------------------------------------------
// z_k encoder — exact fp32 VALU. 512 threads (1 col/thread, 8 rows).
// ---------------------------------------------------------------------------
__global__ __launch_bounds__(512) void encoder_zk_f32(
    const float* __restrict__ xk,
    const float* __restrict__ W1, const float* __restrict__ b1,
    const float* __restrict__ W2, const float* __restrict__ b2,
    const float* __restrict__ W3, const float* __restrict__ b3,
    const float* __restrict__ Wo, const float* __restrict__ bo_,
    float* __restrict__ zk_out) {
  __shared__ __align__(16) float hb[2][8][512];
  __shared__ __align__(16) float xb[8][32];
  const int t = threadIdx.x;
  const int row0 = blockIdx.x * 8;
  if (t < 256) {
    int r = t >> 5, j = t & 31;
    float v = xk[(size_t)(row0 + r) * 32 + j];
    xb[r][j] = v;
    zk_out[(size_t)(row0 + r) * 128 + j] = v;      // x pass-through
  }
  __syncthreads();
  const int c = t;
  // layer 1: K=32
  {
    float a[8];
    const float i0 = b1[c];
    #pragma unroll
    for (int r = 0; r < 8; ++r) a[r] = i0;
    for (int k = 0; k < 32; k += 4) {
      float w0 = W1[(size_t)(k+0)*512 + c];
      float w1 = W1[(size_t)(k+1)*512 + c];
      float w2 = W1[(size_t)(k+2)*512 + c];
      float w3 = W1[(size_t)(k+3)*512 + c];
      #pragma unroll
      for (int r = 0; r < 8; ++r) {
        f32x4 z = *(const f32x4*)&xb[r][k];
        a[r] += z[0]*w0 + z[1]*w1 + z[2]*w2 + z[3]*w3;
      }
    }
    #pragma unroll
    for (int r = 0; r < 8; ++r) hb[0][r][c] = fmaxf(a[r], 0.f);
  }
  __syncthreads();
  // layers 2,3: K=512
  #pragma unroll
  for (int lyr = 0; lyr < 2; ++lyr) {
    const float* W = lyr ? W3 : W2;
    const float* bb = lyr ? b3 : b2;
    const float (*hin)[512] = hb[lyr & 1];
    float (*hout)[512] = hb[(lyr & 1) ^ 1];
    float a[8];
    const float i0 = bb[c];
    #pragma unroll
    for (int r = 0; r < 8; ++r) a[r] = i0;
    for (int k = 0; k < 512; k += 4) {
      float w0 = W[(size_t)(k+0)*512 + c];
      float w1 = W[(size_t)(k+1)*512 + c];
      float w2 = W[(size_t)(k+2)*512 + c];
      float w3 = W[(size_t)(k+3)*512 + c];
      #pragma unroll
      for (int r = 0; r < 8; ++r) {
        f32x4 z = *(const f32x4*)&hin[r][k];
        a[r] += z[0]*w0 + z[1]*w1 + z[2]*w2 + z[3]*w3;
      }
    }
    #pragma unroll
    for (int r = 0; r < 8; ++r) hout[r][c] = fmaxf(a[r], 0.f);
    __syncthreads();
  }
  // output layer: N=96
  if (t < 96) {
    float a[8];
    const float i0 = bo_[t];
    #pragma unroll
    for (int r = 0; r < 8; ++r) a[r] = i0;
    for (int k = 0; k < 512; k += 4) {
      float w0 = Wo[(size_t)(k+0)*96 + t];
      float w1 = Wo[(size_t)(k+1)*96 + t];
      float w2 = Wo[(size_t)(k+2)*96 + t];
      float w3 = Wo[(size_t)(k+3)*96 + t];
      #pragma unroll
      for (int r = 0; r < 8; ++r) {
        f32x4 z = *(const f32x4*)&hb[0][r][k];
        a[r] += z[0]*w0 + z[1]*w1 + z[2]*w2 + z[3]*w3;
      }
    }
    #pragma unroll
    for (int r = 0; r < 8; ++r)
      zk_out[(size_t)(row0 + r) * 128 + 32 + t] = a[r];
  }
}

// ---------------------------------------------------------------------------
// Scan — hi/lo bf16 MFMA (fp32 emulation), one barrier per step (R9).
// ---------------------------------------------------------------------------
__global__ __launch_bounds__(512) void scan_mfma(
    const float* __restrict__ zk, const u16* __restrict__ wf,
    const float* __restrict__ Bm, const float* __restrict__ useq,
    float* __restrict__ zpred, float* __restrict__ xpred) {
  __shared__ __align__(16) u16 ahf[32 * 512];     // 32KB A-hi frags
  __shared__ __align__(16) u16 alf[32 * 512];     // 32KB A-lo frags
  __shared__ __align__(16) float ubuf[8 * 512];   // 16KB u (rows x steps x 8)
  __shared__ __align__(16) u16 zh[2][16][136];    // z hi bf16, ping-pong
  __shared__ __align__(16) u16 zl[2][16][136];    // z lo bf16, ping-pong
  const int t = threadIdx.x;
  const int wv = t >> 6, l = t & 63;
  const int q = l >> 4, n = l & 15;
  const size_t b0 = (size_t)blockIdx.x * 8;

  #pragma unroll
  for (int i = 0; i < 4; ++i) {
    const int f = wv * 4 + i;
    __builtin_amdgcn_global_load_lds(
        (const __attribute__((address_space(1))) unsigned int*)(wf + OFF_AH + (size_t)f * 512 + l * 8),
        (__attribute__((address_space(3))) unsigned int*)(ahf + (size_t)f * 512), 16, 0, 0);
    __builtin_amdgcn_global_load_lds(
        (const __attribute__((address_space(1))) unsigned int*)(wf + OFF_AL + (size_t)f * 512 + l * 8),
        (__attribute__((address_space(3))) unsigned int*)(alf + (size_t)f * 512), 16, 0, 0);
  }
  {
    const float* us = useq + b0 * 512;
    *(f32x4*)&ubuf[t * 8]     = *(const f32x4*)(us + t * 8);
    *(f32x4*)&ubuf[t * 8 + 4] = *(const f32x4*)(us + t * 8 + 4);
  }
  for (int i = t; i < 8 * 136; i += 512) {
    (&zh[0][8][0])[i] = 0; (&zh[1][8][0])[i] = 0;
    (&zl[0][8][0])[i] = 0; (&zl[1][8][0])[i] = 0;
  }
  if (t < 256) {
    const int r = t >> 5, c4 = (t & 31) * 4;
    f32x4 z = *(const f32x4*)(zk + (b0 + r) * 128 + c4);
    #pragma unroll
    for (int i = 0; i < 4; ++i) {
      u16 h = f2bf(z[i]);
      zh[0][r][c4 + i] = h;
      zl[0][r][c4 + i] = f2bf(z[i] - bf2f(h));
    }
  }
  const int myc = wv * 16 + n;
  float bmv[8];
  #pragma unroll
  for (int j = 0; j < 8; ++j) bmv[j] = Bm[(size_t)j * 128 + myc];
  __syncthreads();

  float bunow[4];
  #pragma unroll
  for (int r = 0; r < 4; ++r) {
    const int row = (q & 1) * 4 + r;
    f32x4 ua = *(const f32x4*)&ubuf[row * 512];
    f32x4 ub = *(const f32x4*)&ubuf[row * 512 + 4];
    bunow[r] = ua[0]*bmv[0] + ua[1]*bmv[1] + ua[2]*bmv[2] + ua[3]*bmv[3]
             + ub[0]*bmv[4] + ub[1]*bmv[5] + ub[2]*bmv[6] + ub[3]*bmv[7];
  }

  int cur = 0;
  for (int s = 0; s < 64; ++s) {
    f32x4 aH = {0.f, 0.f, 0.f, 0.f};
    f32x4 aL = {0.f, 0.f, 0.f, 0.f};
    f32x4 aM = {0.f, 0.f, 0.f, 0.f};
    #pragma unroll
    for (int ks = 0; ks < 4; ++ks) {
      const int ko = ks * 32 + q * 8;
      bf16x8 azh = *(const bf16x8*)&zh[cur][n][ko];
      bf16x8 azl = *(const bf16x8*)&zl[cur][n][ko];
      bf16x8 bh = *(const bf16x8*)&ahf[(size_t)(wv * 4 + ks) * 512 + l * 8];
      bf16x8 bl = *(const bf16x8*)&alf[(size_t)(wv * 4 + ks) * 512 + l * 8];
      aH = __builtin_amdgcn_mfma_f32_16x16x32_bf16(azh, bh, aH, 0, 0, 0);
      aL = __builtin_amdgcn_mfma_f32_16x16x32_bf16(azl, bh, aL, 0, 0, 0);
      aM = __builtin_amdgcn_mfma_f32_16x16x32_bf16(azh, bl, aM, 0, 0, 0);
    }
    f32x4 acc = aH + aL;
    acc = acc + aM;
    if (q < 2) {
      #pragma unroll
      for (int r = 0; r < 4; ++r) {
        const int row = q * 4 + r;
        const float v = acc[r] + bunow[r];
        u16 h = f2bf(v);
        zh[cur ^ 1][row][myc] = h;
        zl[cur ^ 1][row][myc] = f2bf(v - bf2f(h));
        const size_t go = (b0 + row) * 64 + s;
        zpred[go * 128 + myc] = v;
        if (wv < 2) xpred[go * 32 + myc] = v;
      }
    }
    if (s < 63) {
      #pragma unroll
      for (int r = 0; r < 4; ++r) {
        const int row = (q & 1) * 4 + r;
        f32x4 ua = *(const f32x4*)&ubuf[row * 512 + (s + 1) * 8];
        f32x4 ub = *(const f32x4*)&ubuf[row * 512 + (s + 1) * 8 + 4];
        bunow[r] = ua[0]*bmv[0] + ua[1]*bmv[1] + ua[2]*bmv[2] + ua[3]*bmv[3]
                 + ub[0]*bmv[4] + ub[1]*bmv[5] + ub[2]*bmv[6] + ub[3]*bmv[7];
      }
    }
    __syncthreads();
    cur ^= 1;
  }
}

// ---------------------------------------------------------------------------
extern "C" void kernel_launch(void* const* d_in, const int* in_sizes, int n_in,
                              void* d_out, int out_size, void* d_ws, size_t ws_size,
                              hipStream_t stream) {
  (void)in_sizes; (void)n_in; (void)out_size; (void)ws_size;
  const float* xk    = (const float*)d_in[0];
  const float* useq  = (const float*)d_in[1];
  const float* xnext = (const float*)d_in[2];
  const float* W1 = (const float*)d_in[3];
  const float* b1 = (const float*)d_in[4];
  const float* W2 = (const float*)d_in[5];
  const float* b2 = (const float*)d_in[6];
  const float* W3 = (const float*)d_in[7];
  const float* b3 = (const float*)d_in[8];
  const float* Wo = (const float*)d_in[9];
  const float* bo = (const float*)d_in[10];
  const float* A  = (const float*)d_in[11];
  const float* Bm = (const float*)d_in[12];

  float* out   = (float*)d_out;
  float* zpred = out;
  float* xpred = out + XPRED_OFF;
  float* ztgt  = out + ZTGT_OFF;
  u16*   wf    = (u16*)d_ws;
  float* zkw   = (float*)((char*)d_ws + OFF_ZK_BYTES);

  prep_swizzle<<<1216, 64, 0, stream>>>(W1, W2, W3, Wo, A, wf);
  encoder_zk_f32<<<256, 512, 0, stream>>>(xk, W1, b1, W2, b2, W3, b3, Wo, bo, zkw);
  scan_mfma<<<256, 512, 0, stream>>>(zkw, wf, Bm, useq, zpred, xpred);
  encoder_tgt<<<2048, 512, 0, stream>>>(xnext, wf, b1, b2, b3, bo, ztgt);
}